// Round 6
// baseline (31.366 us; speedup 1.0000x reference)
//
#include <hip/hip_runtime.h>
#include <hip/hip_bf16.h>

// ---------------------------------------------------------------------------
// QuantumNeuralNetwork: out[b][q] = <psi_b| U^dag Z_q U |psi_b>.
// Kernel 1: build W = [Re(U); Im(U)] as 128x128 bf16 x2 in d_ws, stored in
//           MFMA-A-fragment order (coalesced per-wave preload).
// Kernel 2: persistent blocks (grid = ntiles/4), 32-row tiles, double-buffered
//           fp32 LDS filled by global_load_lds with PRE-SWIZZLED global source
//           (rule #21: linear LDS dest + inverse-swizzled src + swizzled read).
//           Counted s_waitcnt vmcnt(4) keeps next tile's loads in flight
//           across barriers (T4). bf16 conversion at B-frag read time.
// ---------------------------------------------------------------------------

typedef __attribute__((ext_vector_type(8)))  short short8;   // 8 x bf16
typedef __attribute__((ext_vector_type(16))) float f32x16;   // 32x32 acc

static __device__ __forceinline__ short f2bf(float f) {
  __bf16 h = (__bf16)f;
  return __builtin_bit_cast(short, h);
}

static __device__ __forceinline__ void gl16(const void* g, void* l) {
  __builtin_amdgcn_global_load_lds(
      (const __attribute__((address_space(1))) void*)g,
      (__attribute__((address_space(3))) void*)l, 16, 0, 0);
}

// A-fragment layout: frag(P, wv=s>>5, j=k>>4); lane = (s&31) + 32*((k>>3)&1);
// elem = k&7.  Flat short index:
static __device__ __forceinline__ int widx(int P, int s, int k) {
  return ((((P << 2) + (s >> 5)) * 8 + (k >> 4)) * 64 +
          ((s & 31) + ((k >> 3) & 1) * 32)) * 8 + (k & 7);
}

// ------------------------------- kernel 1 ----------------------------------
// 128 blocks (one column k each) x 64 threads. Lane l holds states 2l, 2l+1.
__global__ void qnn_build_w(const float* __restrict__ wts,
                            short* __restrict__ W) {
  const int k = blockIdx.x;
  const int l = threadIdx.x;

  float c0r = (2 * l     == k) ? 1.f : 0.f, c0i = 0.f;
  float c1r = (2 * l + 1 == k) ? 1.f : 0.f, c1i = 0.f;

  for (int layer = 0; layer < 2; ++layer) {
    for (int q = 0; q < 7; ++q) {
      const float t0 = 0.5f * wts[(layer * 7 + q) * 3 + 0];
      const float t1 = 0.5f * wts[(layer * 7 + q) * 3 + 1];
      const float t2 = 0.5f * wts[(layer * 7 + q) * 3 + 2];
      const float cx = __cosf(t0), sx = __sinf(t0);
      const float cy = __cosf(t1), sy = __sinf(t1);
      const float cz = __cosf(t2), sz = __sinf(t2);
      const float m00r =  cy * cx, m00i =  sy * sx;
      const float m01r = -sy * cx, m01i = -cy * sx;
      const float m10r =  sy * cx, m10i = -cy * sx;
      const float m11r =  cy * cx, m11i = -sy * sx;
      const float g00r = m00r * cz + m00i * sz, g00i = m00i * cz - m00r * sz;
      const float g01r = m01r * cz + m01i * sz, g01i = m01i * cz - m01r * sz;
      const float g10r = m10r * cz - m10i * sz, g10i = m10i * cz + m10r * sz;
      const float g11r = m11r * cz - m11i * sz, g11i = m11i * cz + m11r * sz;

      const int b = 6 - q;
      if (b == 0) {
        const float n0r = g00r*c0r - g00i*c0i + g01r*c1r - g01i*c1i;
        const float n0i = g00r*c0i + g00i*c0r + g01r*c1i + g01i*c1r;
        const float n1r = g10r*c0r - g10i*c0i + g11r*c1r - g11i*c1i;
        const float n1i = g10r*c0i + g10i*c0r + g11r*c1i + g11i*c1r;
        c0r = n0r; c0i = n0i; c1r = n1r; c1i = n1i;
      } else {
        const int xm  = 1 << (b - 1);
        const int myb = (l >> (b - 1)) & 1;
        const float p0r = __shfl_xor(c0r, xm), p0i = __shfl_xor(c0i, xm);
        const float p1r = __shfl_xor(c1r, xm), p1i = __shfl_xor(c1i, xm);
        const float gar = myb ? g11r : g00r, gai = myb ? g11i : g00i;
        const float gbr = myb ? g10r : g01r, gbi = myb ? g10i : g01i;
        const float n0r = gar*c0r - gai*c0i + gbr*p0r - gbi*p0i;
        const float n0i = gar*c0i + gai*c0r + gbr*p0i + gbi*p0r;
        const float n1r = gar*c1r - gai*c1i + gbr*p1r - gbi*p1i;
        const float n1i = gar*c1i + gai*c1r + gbr*p1i + gbi*p1r;
        c0r = n0r; c0i = n0i; c1r = n1r; c1i = n1i;
      }
    }
    #pragma unroll
    for (int q = 0; q < 7; ++q) {
      const int bc = 6 - q;
      const int bt = 6 - ((q + 1) % 7);
      if (bt == 0) {
        if (l & 1) { float tr=c0r, ti=c0i; c0r=c1r; c0i=c1i; c1r=tr; c1i=ti; }
      } else if (bc == 0) {
        c1r = __shfl_xor(c1r, 32);
        c1i = __shfl_xor(c1i, 32);
      } else {
        const int xm = 1 << (bt - 1);
        const float p0r = __shfl_xor(c0r, xm), p0i = __shfl_xor(c0i, xm);
        const float p1r = __shfl_xor(c1r, xm), p1i = __shfl_xor(c1i, xm);
        if ((l >> (bc - 1)) & 1) { c0r=p0r; c0i=p0i; c1r=p1r; c1i=p1i; }
      }
    }
  }

  W[widx(0, 2 * l,     k)] = f2bf(c0r);
  W[widx(0, 2 * l + 1, k)] = f2bf(c1r);
  W[widx(1, 2 * l,     k)] = f2bf(c0i);
  W[widx(1, 2 * l + 1, k)] = f2bf(c1i);
}

// ------------------------------- kernel 2 ----------------------------------
// 256 threads (4 waves), 4 tiles of 32 rows per block (persistent).
// Swizzle (within a 512B row r): 32B chunk q32 ^= (r&7); 16B half ^= (r>>3)&1.
// Applied on the global SOURCE address of gl16 (LDS dest stays lane-linear)
// and inverted on the ds_read side -> <=2-way bank conflicts per 16-lane
// phase for the row-strided B-frag reads.
__global__ __launch_bounds__(256, 4) void qnn_main(
    const float* __restrict__ x, const short* __restrict__ W,
    float* __restrict__ out, int ntiles) {
  const int tid = threadIdx.x;
  const int l   = tid & 63;
  const int wv  = tid >> 6;
  const int col = l & 31;
  const int h   = l >> 5;

  __shared__ float xb[2][4096];    // 2 x (32 rows x 128 f32), 32 KiB
  __shared__ float red[4][32][7];  // 3.5 KiB

  const int T0 = blockIdx.x * 4;
  const int NT = min(4, ntiles - T0);

  // ---- A-preload FIRST (oldest vmcnt entries; drained by first vmcnt(4))
  short8 A0[8], A1[8];
  #pragma unroll
  for (int j = 0; j < 8; ++j) {
    const int off = ((wv * 8 + j) * 64 + l) * 8;
    A0[j] = *reinterpret_cast<const short8*>(W + off);
    A1[j] = *reinterpret_cast<const short8*>(W + 16384 + off);
  }

  // ---- async HBM -> LDS stage for one 32-row tile (4 x gl16 per thread)
  auto ISSUE = [&](int T, int b) {
    const char* gbase = (const char*)(x + (size_t)T * 32 * 128);
    char* lbase = (char*)&xb[b][0];
    #pragma unroll
    for (int i = 0; i < 4; ++i) {
      const int d   = i * 4096 + tid * 16;      // linear LDS dest byte
      const int r   = d >> 9;                   // row 0..31
      const int c16 = (d >> 4) & 31;            // 16B chunk in row
      const int q32 = c16 >> 1, hf = c16 & 1;
      const int qg  = q32 ^ (r & 7);            // inverse swizzle on source
      const int hg  = hf  ^ ((r >> 3) & 1);
      gl16(gbase + r * 512 + qg * 32 + hg * 16, lbase + d);
    }
  };

  if (NT > 0) ISSUE(T0, 0);
  if (NT > 1) ISSUE(T0 + 1, 1);

  for (int i = 0; i < NT; ++i) {
    const int p = i & 1;

    // buf[p] ready when this wave's older loads drain; keep newest 4 in flight
    if (i + 1 < NT) { asm volatile("s_waitcnt vmcnt(4)" ::: "memory"); }
    else            { asm volatile("s_waitcnt vmcnt(0)" ::: "memory"); }
    __builtin_amdgcn_s_barrier();
    asm volatile("" ::: "memory");

    // ---- compute: 16 ds_read_b128-pairs -> cvt -> 16 MFMA, Walsh epilogue
    f32x16 acc0 = {0.f,0.f,0.f,0.f,0.f,0.f,0.f,0.f,
                   0.f,0.f,0.f,0.f,0.f,0.f,0.f,0.f};
    f32x16 acc1 = {0.f,0.f,0.f,0.f,0.f,0.f,0.f,0.f,
                   0.f,0.f,0.f,0.f,0.f,0.f,0.f,0.f};
    {
      const int hb = (col >> 3) & 1;
      const char* xrow = (const char*)&xb[p][0] + col * 512;
      #pragma unroll
      for (int j = 0; j < 8; ++j) {
        const int qg  = j * 2 + h;                 // 32B chunk (8 floats)
        const int q32 = qg ^ (col & 7);
        const float4 f0 = *reinterpret_cast<const float4*>(
            xrow + q32 * 32 + hb * 16);            // floats 0..3
        const float4 f1 = *reinterpret_cast<const float4*>(
            xrow + q32 * 32 + (hb ^ 1) * 16);      // floats 4..7
        short8 bfr;
        bfr[0]=f2bf(f0.x); bfr[1]=f2bf(f0.y); bfr[2]=f2bf(f0.z); bfr[3]=f2bf(f0.w);
        bfr[4]=f2bf(f1.x); bfr[5]=f2bf(f1.y); bfr[6]=f2bf(f1.z); bfr[7]=f2bf(f1.w);
        acc0 = __builtin_amdgcn_mfma_f32_32x32x16_bf16(A0[j], bfr, acc0, 0, 0, 0);
        acc1 = __builtin_amdgcn_mfma_f32_32x32x16_bf16(A1[j], bfr, acc1, 0, 0, 0);
      }
    }

    // Walsh tree over s-bits (verified rounds 0-5)
    {
      float aS[8], aD[8];
      #pragma unroll
      for (int i2 = 0; i2 < 8; ++i2) {
        const float pe = acc0[2*i2]   * acc0[2*i2]   + acc1[2*i2]   * acc1[2*i2];
        const float po = acc0[2*i2+1] * acc0[2*i2+1] + acc1[2*i2+1] * acc1[2*i2+1];
        aS[i2] = pe + po;
        aD[i2] = pe - po;
      }
      float bS[4], bD[4];
      #pragma unroll
      for (int i2 = 0; i2 < 4; ++i2) {
        bS[i2] = aS[2*i2] + aS[2*i2+1];
        bD[i2] = aS[2*i2] - aS[2*i2+1];
      }
      float u0 = ((aD[0]+aD[1]) + (aD[2]+aD[3])) + ((aD[4]+aD[5]) + (aD[6]+aD[7]));
      float u1 = (bD[0] + bD[1]) + (bD[2] + bD[3]);
      const float cS0 = bS[0] + bS[1], cD0 = bS[0] - bS[1];
      const float cS1 = bS[2] + bS[3], cD1 = bS[2] - bS[3];
      float u3 = cD0 + cD1;
      float u4 = cS0 - cS1;
      float T  = cS0 + cS1;

      const float Tp = __shfl_xor(T, 32);
      const float u2 = h ? (Tp - T) : (T - Tp);
      T += Tp;
      u0 += __shfl_xor(u0, 32);
      u1 += __shfl_xor(u1, 32);
      u3 += __shfl_xor(u3, 32);
      u4 += __shfl_xor(u4, 32);

      if (h == 0) {
        red[wv][col][0] = T;
        red[wv][col][1] = u0;
        red[wv][col][2] = u1;
        red[wv][col][3] = u2;
        red[wv][col][4] = u3;
        red[wv][col][5] = u4;
      }
    }

    asm volatile("s_waitcnt lgkmcnt(0)" ::: "memory");
    __builtin_amdgcn_s_barrier();      // red ready AND xb[p] fully consumed
    asm volatile("" ::: "memory");

    // ---- tail stores BEFORE next issue: keeps vmcnt order
    //      [g(t+1) : stores : g(t+2)] so vmcnt(4) = "tile t+1 ready".
    if (tid < 32) {
      const int c = tid;
      const float T0v = red[0][c][0], T1v = red[1][c][0];
      const float T2v = red[2][c][0], T3v = red[3][c][0];
      const float sT  = (T0v + T1v) + (T2v + T3v);
      const float inv = 1.0f / sT;     // == 1/||x||^2 (unitarity)
      const float z0 = (T0v + T1v) - (T2v + T3v);
      const float z1 = (T0v - T1v) + (T2v - T3v);
      float zr[5];
      #pragma unroll
      for (int i2 = 0; i2 < 5; ++i2)
        zr[i2] = (red[0][c][5-i2] + red[1][c][5-i2]) +
                 (red[2][c][5-i2] + red[3][c][5-i2]);
      float* o = out + (size_t)((T0 + i) * 32 + c) * 7;
      o[0] = z0 * inv; o[1] = z1 * inv; o[2] = zr[0] * inv; o[3] = zr[1] * inv;
      o[4] = zr[2] * inv; o[5] = zr[3] * inv; o[6] = zr[4] * inv;
    }

    if (i + 2 < NT) ISSUE(T0 + i + 2, p);   // overwrite consumed buffer
  }
}

// ------------------------------- launcher ----------------------------------
extern "C" void kernel_launch(void* const* d_in, const int* in_sizes, int n_in,
                              void* d_out, int out_size, void* d_ws, size_t ws_size,
                              hipStream_t stream) {
  const float* x   = (const float*)d_in[0];
  const float* wts = (const float*)d_in[1];
  float* out = (float*)d_out;
  short* W   = (short*)d_ws;               // 2 * 128*128 bf16 = 64 KiB

  const int B      = in_sizes[0] / 128;
  const int ntiles = B / 32;               // 32-row tiles
  const int grid   = (ntiles + 3) / 4;     // 4 tiles per persistent block

  qnn_build_w<<<128, 64, 0, stream>>>(wts, W);
  qnn_main<<<grid, 256, 0, stream>>>(x, W, out, ntiles);
}

// Round 7
// 25.546 us; speedup vs baseline: 1.2278x; 1.2278x over previous
//
#include <hip/hip_runtime.h>
#include <hip/hip_bf16.h>

// ---------------------------------------------------------------------------
// QuantumNeuralNetwork: out[b][q] = <psi_b| U^dag Z_q U |psi_b>.
// Kernel 1: build W = [Re(U); Im(U)] as 128x128 bf16 x2 in d_ws, stored in
//           MFMA-A-fragment order (coalesced per-wave preload).
// Kernel 2: ONE 32-row tile per block (grid = B/32 = 4096). Block does:
//           issue x loads -> A preload -> stage bf16 to swizzled LDS ->
//           barrier -> 16 MFMA + Walsh epilogue -> barrier -> tail write.
//           Latency hiding from 4 blocks/CU TLP (16 waves/CU); small tiles
//           keep the per-block load drain short (16 KB).
// ---------------------------------------------------------------------------

typedef __attribute__((ext_vector_type(8)))  short short8;   // 8 x bf16
typedef __attribute__((ext_vector_type(16))) float f32x16;   // 32x32 acc

static __device__ __forceinline__ short f2bf(float f) {
  __bf16 h = (__bf16)f;
  return __builtin_bit_cast(short, h);
}

// A-fragment layout: frag(P, wv=s>>5, j=k>>4); lane = (s&31) + 32*((k>>3)&1);
// elem = k&7.  Flat short index:
static __device__ __forceinline__ int widx(int P, int s, int k) {
  return ((((P << 2) + (s >> 5)) * 8 + (k >> 4)) * 64 +
          ((s & 31) + ((k >> 3) & 1) * 32)) * 8 + (k & 7);
}

// ------------------------------- kernel 1 ----------------------------------
// 128 blocks (one column k each) x 64 threads. Lane l holds states 2l, 2l+1.
__global__ void qnn_build_w(const float* __restrict__ wts,
                            short* __restrict__ W) {
  const int k = blockIdx.x;
  const int l = threadIdx.x;

  float c0r = (2 * l     == k) ? 1.f : 0.f, c0i = 0.f;
  float c1r = (2 * l + 1 == k) ? 1.f : 0.f, c1i = 0.f;

  for (int layer = 0; layer < 2; ++layer) {
    for (int q = 0; q < 7; ++q) {
      const float t0 = 0.5f * wts[(layer * 7 + q) * 3 + 0];
      const float t1 = 0.5f * wts[(layer * 7 + q) * 3 + 1];
      const float t2 = 0.5f * wts[(layer * 7 + q) * 3 + 2];
      const float cx = __cosf(t0), sx = __sinf(t0);
      const float cy = __cosf(t1), sy = __sinf(t1);
      const float cz = __cosf(t2), sz = __sinf(t2);
      const float m00r =  cy * cx, m00i =  sy * sx;
      const float m01r = -sy * cx, m01i = -cy * sx;
      const float m10r =  sy * cx, m10i = -cy * sx;
      const float m11r =  cy * cx, m11i = -sy * sx;
      const float g00r = m00r * cz + m00i * sz, g00i = m00i * cz - m00r * sz;
      const float g01r = m01r * cz + m01i * sz, g01i = m01i * cz - m01r * sz;
      const float g10r = m10r * cz - m10i * sz, g10i = m10i * cz + m10r * sz;
      const float g11r = m11r * cz - m11i * sz, g11i = m11i * cz + m11r * sz;

      const int b = 6 - q;
      if (b == 0) {
        const float n0r = g00r*c0r - g00i*c0i + g01r*c1r - g01i*c1i;
        const float n0i = g00r*c0i + g00i*c0r + g01r*c1i + g01i*c1r;
        const float n1r = g10r*c0r - g10i*c0i + g11r*c1r - g11i*c1i;
        const float n1i = g10r*c0i + g10i*c0r + g11r*c1i + g11i*c1r;
        c0r = n0r; c0i = n0i; c1r = n1r; c1i = n1i;
      } else {
        const int xm  = 1 << (b - 1);
        const int myb = (l >> (b - 1)) & 1;
        const float p0r = __shfl_xor(c0r, xm), p0i = __shfl_xor(c0i, xm);
        const float p1r = __shfl_xor(c1r, xm), p1i = __shfl_xor(c1i, xm);
        const float gar = myb ? g11r : g00r, gai = myb ? g11i : g00i;
        const float gbr = myb ? g10r : g01r, gbi = myb ? g10i : g01i;
        const float n0r = gar*c0r - gai*c0i + gbr*p0r - gbi*p0i;
        const float n0i = gar*c0i + gai*c0r + gbr*p0i + gbi*p0r;
        const float n1r = gar*c1r - gai*c1i + gbr*p1r - gbi*p1i;
        const float n1i = gar*c1i + gai*c1r + gbr*p1i + gbi*p1r;
        c0r = n0r; c0i = n0i; c1r = n1r; c1i = n1i;
      }
    }
    #pragma unroll
    for (int q = 0; q < 7; ++q) {
      const int bc = 6 - q;
      const int bt = 6 - ((q + 1) % 7);
      if (bt == 0) {
        if (l & 1) { float tr=c0r, ti=c0i; c0r=c1r; c0i=c1i; c1r=tr; c1i=ti; }
      } else if (bc == 0) {
        c1r = __shfl_xor(c1r, 32);
        c1i = __shfl_xor(c1i, 32);
      } else {
        const int xm = 1 << (bt - 1);
        const float p0r = __shfl_xor(c0r, xm), p0i = __shfl_xor(c0i, xm);
        const float p1r = __shfl_xor(c1r, xm), p1i = __shfl_xor(c1i, xm);
        if ((l >> (bc - 1)) & 1) { c0r=p0r; c0i=p0i; c1r=p1r; c1i=p1i; }
      }
    }
  }

  W[widx(0, 2 * l,     k)] = f2bf(c0r);
  W[widx(0, 2 * l + 1, k)] = f2bf(c1r);
  W[widx(1, 2 * l,     k)] = f2bf(c0i);
  W[widx(1, 2 * l + 1, k)] = f2bf(c1i);
}

// ------------------------------- kernel 2 ----------------------------------
// 256 threads (4 waves), ONE 32-row tile per block. Wave wv owns states
// [32wv,32wv+32) (A-frags, 64 VGPRs, coalesced fragment-order load).
// x loads: p = i*256+tid, row = p>>4, chunk = p&15 -> each wave instruction
// reads a contiguous aligned 1 KiB (verified best coalescing, rounds 1-5).
__global__ __launch_bounds__(256, 4) void qnn_main(
    const float* __restrict__ x, const short* __restrict__ W,
    float* __restrict__ out) {
  const int tid = threadIdx.x;
  const int l   = tid & 63;
  const int wv  = tid >> 6;
  const int col = l & 31;
  const int h   = l >> 5;

  __shared__ short8 xb[512];          // 32 rows x 16 chunks (swizzled), 8 KiB
  __shared__ float  red[4][32][7];    // pad 7: conflict-free TAIL, 3.5 KiB

  const int t0 = blockIdx.x;

  // ---- issue x loads first (HBM latency starts now); contiguous mapping
  float4 fa[2], fb[2];
  #pragma unroll
  for (int i = 0; i < 2; ++i) {
    const int p = i * 256 + tid;
    const int r = p >> 4, q = p & 15;
    const float* gp = x + (size_t)(t0 * 32 + r) * 128 + q * 8;
    fa[i] = *reinterpret_cast<const float4*>(gp);
    fb[i] = *reinterpret_cast<const float4*>(gp + 4);
  }

  // ---- A-preload: coalesced fragment-order reads (W is L2-resident)
  short8 A0[8], A1[8];
  #pragma unroll
  for (int j = 0; j < 8; ++j) {
    const int off = ((wv * 8 + j) * 64 + l) * 8;
    A0[j] = *reinterpret_cast<const short8*>(W + off);
    A1[j] = *reinterpret_cast<const short8*>(W + 16384 + off);
  }

  // ---- stage: fp32 regs -> bf16 swizzled LDS
  #pragma unroll
  for (int i = 0; i < 2; ++i) {
    const int p = i * 256 + tid;
    const int r = p >> 4, q = p & 15;
    short8 c;
    c[0]=f2bf(fa[i].x); c[1]=f2bf(fa[i].y); c[2]=f2bf(fa[i].z); c[3]=f2bf(fa[i].w);
    c[4]=f2bf(fb[i].x); c[5]=f2bf(fb[i].y); c[6]=f2bf(fb[i].z); c[7]=f2bf(fb[i].w);
    xb[r * 16 + (q ^ (r & 7))] = c;
  }
  asm volatile("s_waitcnt lgkmcnt(0)" ::: "memory");
  __builtin_amdgcn_s_barrier();
  asm volatile("" ::: "memory");

  // ---- compute: 16 ds_read_b128 -> 16 MFMA, then Walsh-tree epilogue
  f32x16 acc0 = {0.f,0.f,0.f,0.f,0.f,0.f,0.f,0.f,
                 0.f,0.f,0.f,0.f,0.f,0.f,0.f,0.f};
  f32x16 acc1 = {0.f,0.f,0.f,0.f,0.f,0.f,0.f,0.f,
                 0.f,0.f,0.f,0.f,0.f,0.f,0.f,0.f};
  #pragma unroll
  for (int j = 0; j < 8; ++j) {
    const int q = j * 2 + h;
    const short8 bfr = xb[col * 16 + (q ^ (col & 7))];
    acc0 = __builtin_amdgcn_mfma_f32_32x32x16_bf16(A0[j], bfr, acc0, 0, 0, 0);
    acc1 = __builtin_amdgcn_mfma_f32_32x32x16_bf16(A1[j], bfr, acc1, 0, 0, 0);
  }

  // Walsh tree over s-bits (verified rounds 0-6)
  {
    float aS[8], aD[8];
    #pragma unroll
    for (int i = 0; i < 8; ++i) {
      const float pe = acc0[2*i]   * acc0[2*i]   + acc1[2*i]   * acc1[2*i];
      const float po = acc0[2*i+1] * acc0[2*i+1] + acc1[2*i+1] * acc1[2*i+1];
      aS[i] = pe + po;
      aD[i] = pe - po;
    }
    float bS[4], bD[4];
    #pragma unroll
    for (int i = 0; i < 4; ++i) {
      bS[i] = aS[2*i] + aS[2*i+1];
      bD[i] = aS[2*i] - aS[2*i+1];
    }
    float u0 = ((aD[0]+aD[1]) + (aD[2]+aD[3])) + ((aD[4]+aD[5]) + (aD[6]+aD[7]));
    float u1 = (bD[0] + bD[1]) + (bD[2] + bD[3]);
    const float cS0 = bS[0] + bS[1], cD0 = bS[0] - bS[1];
    const float cS1 = bS[2] + bS[3], cD1 = bS[2] - bS[3];
    float u3 = cD0 + cD1;
    float u4 = cS0 - cS1;
    float T  = cS0 + cS1;

    const float Tp = __shfl_xor(T, 32);
    const float u2 = h ? (Tp - T) : (T - Tp);
    T += Tp;
    u0 += __shfl_xor(u0, 32);
    u1 += __shfl_xor(u1, 32);
    u3 += __shfl_xor(u3, 32);
    u4 += __shfl_xor(u4, 32);

    if (h == 0) {
      red[wv][col][0] = T;
      red[wv][col][1] = u0;
      red[wv][col][2] = u1;
      red[wv][col][3] = u2;
      red[wv][col][4] = u3;
      red[wv][col][5] = u4;
    }
  }

  asm volatile("s_waitcnt lgkmcnt(0)" ::: "memory");
  __builtin_amdgcn_s_barrier();
  asm volatile("" ::: "memory");

  // ---- tail: combine across waves (s-bits b5,b6), write 7 outs x 32 rows
  if (tid < 32) {
    const int c = tid;
    const float T0 = red[0][c][0], T1 = red[1][c][0];
    const float T2 = red[2][c][0], T3 = red[3][c][0];
    const float sT  = (T0 + T1) + (T2 + T3);
    const float inv = 1.0f / sT;            // == 1/||x||^2 (unitarity)
    const float z0 = (T0 + T1) - (T2 + T3);
    const float z1 = (T0 - T1) + (T2 - T3);
    float zr[5];
    #pragma unroll
    for (int i = 0; i < 5; ++i)
      zr[i] = (red[0][c][5-i] + red[1][c][5-i]) +
              (red[2][c][5-i] + red[3][c][5-i]);
    float* o = out + (size_t)(t0 * 32 + c) * 7;
    o[0] = z0 * inv; o[1] = z1 * inv; o[2] = zr[0] * inv; o[3] = zr[1] * inv;
    o[4] = zr[2] * inv; o[5] = zr[3] * inv; o[6] = zr[4] * inv;
  }
}

// ------------------------------- launcher ----------------------------------
extern "C" void kernel_launch(void* const* d_in, const int* in_sizes, int n_in,
                              void* d_out, int out_size, void* d_ws, size_t ws_size,
                              hipStream_t stream) {
  const float* x   = (const float*)d_in[0];
  const float* wts = (const float*)d_in[1];
  float* out = (float*)d_out;
  short* W   = (short*)d_ws;               // 2 * 128*128 bf16 = 64 KiB

  const int B     = in_sizes[0] / 128;
  const int grid  = B / 32;                // one 32-row tile per block

  qnn_build_w<<<128, 64, 0, stream>>>(wts, W);
  qnn_main<<<grid, 256, 0, stream>>>(x, W, out);
}